// Round 8
// baseline (265.903 us; speedup 1.0000x reference)
//
#include <hip/hip_runtime.h>
#include <hip/hip_bf16.h>

#define BB 8
#define SS 512
#define HIDV 768
#define HH 12
#define DD 64
#define LV 81

typedef __attribute__((ext_vector_type(8))) short short8v;
typedef __attribute__((ext_vector_type(4))) short short4v;
typedef __attribute__((ext_vector_type(4))) float f32x4;

#define MFMA16(a, b, c) __builtin_amdgcn_mfma_f32_16x16x32_bf16(a, b, c, 0, 0, 0)

__device__ __forceinline__ short f2bf(float f) {
    __hip_bfloat16 h = __float2bfloat16(f);
    return *reinterpret_cast<short*>(&h);
}
__device__ __forceinline__ float bf2f(short s) {
    __hip_bfloat16 h = *reinterpret_cast<__hip_bfloat16*>(&s);
    return __bfloat162float(h);
}
__device__ __forceinline__ void gload16(const void* g, void* l) {
    __builtin_amdgcn_global_load_lds((const __attribute__((address_space(1))) void*)g,
                                     (__attribute__((address_space(3))) void*)l, 16, 0, 0);
}
// HW fp32 LDS atomic (ds_add_f32) — avoids the CAS-loop lowering of plain atomicAdd.
__device__ __forceinline__ void ldsAdd(float* p, float v) {
    unsafeAtomicAdd(p, v);
}

// ---------------- Kernel A: LN tables -> lnkb bf16 [96][64], lnvT128 bf16 [64][128] ----------------
__global__ __launch_bounds__(256) void prep_ln_kernel(
    const float* __restrict__ rel_k, const float* __restrict__ rel_v,
    const float* __restrict__ gk, const float* __restrict__ bk,
    const float* __restrict__ gv, const float* __restrict__ bv,
    short* __restrict__ lnkb, short* __restrict__ lnvT128) {
    __shared__ float ln_lds[2 * LV][DD];
    int t = threadIdx.x;
    if (t < 2 * LV) {
        bool isv = (t >= LV);
        int r = isv ? t - LV : t;
        const float* row = (isv ? rel_v : rel_k) + r * DD;
        const float* g = isv ? gv : gk;
        const float* be = isv ? bv : bk;
        float mu = 0.f;
        for (int d = 0; d < DD; ++d) mu += row[d];
        mu *= (1.f / DD);
        float var = 0.f;
        for (int d = 0; d < DD; ++d) { float x = row[d] - mu; var += x * x; }
        var *= (1.f / DD);
        float rs = rsqrtf(var + 1e-5f);
        for (int d = 0; d < DD; ++d) ln_lds[t][d] = (row[d] - mu) * rs * g[d] + be[d];
    }
    __syncthreads();
    for (int i = t; i < 96 * DD; i += 256) {
        int l = i >> 6, d = i & 63;
        lnkb[i] = (l < LV) ? f2bf(ln_lds[l][d]) : (short)0;
    }
    for (int i = t; i < DD * 128; i += 256) {
        int d = i >> 7, l = i & 127;
        lnvT128[i] = (l < LV) ? f2bf(ln_lds[LV + l][d]) : (short)0;
    }
}

// ---------------- hidden f32 -> bf16 ----------------
__global__ __launch_bounds__(256) void conv_hidden_kernel(const float* __restrict__ in,
                                                          short* __restrict__ out) {
    int i = (blockIdx.x * 256 + threadIdx.x) * 4;
    float4 v = *reinterpret_cast<const float4*>(&in[i]);
    short4v o; o[0] = f2bf(v.x); o[1] = f2bf(v.y); o[2] = f2bf(v.z); o[3] = f2bf(v.w);
    *reinterpret_cast<short4v*>(&out[i]) = o;
}

// ---------------- W [k][n] f32 -> WT [n][k] bf16 (x3 via z) ----------------
__global__ __launch_bounds__(256) void transw_kernel(
    const float* __restrict__ Wq, const float* __restrict__ Wk, const float* __restrict__ Wv,
    short* __restrict__ WqT, short* __restrict__ WkT, short* __restrict__ WvT) {
    const float* W; short* O;
    if (blockIdx.z == 0) { W = Wq; O = WqT; }
    else if (blockIdx.z == 1) { W = Wk; O = WkT; }
    else { W = Wv; O = WvT; }
    __shared__ float tile[32][33];
    int k0 = blockIdx.y * 32, n0 = blockIdx.x * 32;
    int t = threadIdx.x;
    int r = t >> 3, c4 = (t & 7) * 4;
    float4 v = *reinterpret_cast<const float4*>(&W[(size_t)(k0 + r) * HIDV + n0 + c4]);
    tile[r][c4 + 0] = v.x; tile[r][c4 + 1] = v.y; tile[r][c4 + 2] = v.z; tile[r][c4 + 3] = v.w;
    __syncthreads();
    short4v o;
    o[0] = f2bf(tile[c4 + 0][r]); o[1] = f2bf(tile[c4 + 1][r]);
    o[2] = f2bf(tile[c4 + 2][r]); o[3] = f2bf(tile[c4 + 3][r]);
    *reinterpret_cast<short4v*>(&O[(size_t)(n0 + r) * HIDV + k0 + c4]) = o;
}

// ---------------- arc int32 [b][q][k] -> arcQ u32 [b][q>>2][k]: byte r = label(q=4*q4+r, k) ----------------
__global__ __launch_bounds__(256) void arcq_kernel(const int* __restrict__ arc,
                                                   unsigned int* __restrict__ arcQ) {
    __shared__ unsigned char t8[64][68];
    const int tid = threadIdx.x;
    const int b = blockIdx.z;
    const int q0 = blockIdx.y * 64, k0 = blockIdx.x * 64;
    for (int i = tid; i < 64 * 16; i += 256) {
        int q = i >> 4, kc = (i & 15) * 4;
        int4 v = *reinterpret_cast<const int4*>(&arc[((size_t)(b * SS) + q0 + q) * SS + k0 + kc]);
        t8[kc + 0][q] = (unsigned char)v.x;
        t8[kc + 1][q] = (unsigned char)v.y;
        t8[kc + 2][q] = (unsigned char)v.z;
        t8[kc + 3][q] = (unsigned char)v.w;
    }
    __syncthreads();
    {
        int q4 = tid >> 4, kb = (tid & 15) * 4;
        uint4 o;
        o.x = *reinterpret_cast<const unsigned int*>(&t8[kb + 0][4 * q4]);
        o.y = *reinterpret_cast<const unsigned int*>(&t8[kb + 1][4 * q4]);
        o.z = *reinterpret_cast<const unsigned int*>(&t8[kb + 2][4 * q4]);
        o.w = *reinterpret_cast<const unsigned int*>(&t8[kb + 3][4 * q4]);
        *reinterpret_cast<uint4*>(&arcQ[((size_t)b * 128 + (q0 >> 2) + q4) * SS + k0 + kb]) = o;
    }
}

// ---------------- QKV GEMM bf16 MFMA (unchanged, proven) ----------------
__global__ __launch_bounds__(256) void qkv_gemm_kernel(
    const short* __restrict__ Abf,
    const short* __restrict__ WqT, const short* __restrict__ WkT, const short* __restrict__ WvT,
    const float* __restrict__ bq, const float* __restrict__ bk, const float* __restrict__ bv,
    short* __restrict__ qo, short* __restrict__ ko, short* __restrict__ vto) {
    const short* Bt; const float* bias;
    int z = blockIdx.z;
    if (z == 0) { Bt = WqT; bias = bq; }
    else if (z == 1) { Bt = WkT; bias = bk; }
    else { Bt = WvT; bias = bv; }

    __shared__ short smem[8192];
    short* As = smem;
    short* Bs = smem + 4096;

    const int tid = threadIdx.x;
    const int lane = tid & 63, w = tid >> 6;
    const int li = lane & 15, g = lane >> 4;
    const int wr = w >> 1, wc = w & 1;
    const int m0 = blockIdx.y * 64, n0 = blockIdx.x * 64;

    f32x4 acc[2][2];
    for (int ra = 0; ra < 2; ++ra)
        for (int cb = 0; cb < 2; ++cb)
            for (int r = 0; r < 4; ++r) acc[ra][cb][r] = 0.f;

#pragma unroll 1
    for (int k0 = 0; k0 < HIDV; k0 += 64) {
#pragma unroll
        for (int j = 0; j < 2; ++j) {
            int c = j * 256 + tid;
            int row = c >> 3, s = c & 7;
            int src = s ^ (row & 7);
            gload16(Abf + (size_t)(m0 + row) * HIDV + k0 + src * 8, As + c * 8);
            gload16(Bt + (size_t)(n0 + row) * HIDV + k0 + src * 8, Bs + c * 8);
        }
        __syncthreads();
#pragma unroll
        for (int c = 0; c < 2; ++c) {
            short8v af[2], bf[2];
#pragma unroll
            for (int ra = 0; ra < 2; ++ra) {
                int row = 32 * wr + 16 * ra + li;
                int chunk = (4 * c + g) ^ (row & 7);
                af[ra] = *reinterpret_cast<const short8v*>(&As[row * 64 + chunk * 8]);
            }
#pragma unroll
            for (int cb = 0; cb < 2; ++cb) {
                int rowb = 32 * wc + 16 * cb + li;
                int chunk = (4 * c + g) ^ (rowb & 7);
                bf[cb] = *reinterpret_cast<const short8v*>(&Bs[rowb * 64 + chunk * 8]);
            }
#pragma unroll
            for (int ra = 0; ra < 2; ++ra)
#pragma unroll
                for (int cb = 0; cb < 2; ++cb)
                    acc[ra][cb] = MFMA16(af[ra], bf[cb], acc[ra][cb]);
        }
        __syncthreads();
    }

    const int h = n0 >> 6;
    const int bidx = m0 >> 9;
    if (z < 2) {
        short* dst = (z == 0) ? qo : ko;
        float sc = (z == 0) ? 1.f : 0.125f;
#pragma unroll
        for (int ra = 0; ra < 2; ++ra)
#pragma unroll
            for (int cb = 0; cb < 2; ++cb) {
                int n = 32 * wc + 16 * cb + li;
                float bv_ = bias[n0 + n];
#pragma unroll
                for (int r = 0; r < 4; ++r) {
                    int m = m0 + 32 * wr + 16 * ra + 4 * g + r;
                    int s = m & 511;
                    dst[(((size_t)bidx * HH + h) * SS + s) * DD + n] =
                        f2bf((acc[ra][cb][r] + bv_) * sc);
                }
            }
    } else {
        short* Cs = smem;
#pragma unroll
        for (int ra = 0; ra < 2; ++ra)
#pragma unroll
            for (int cb = 0; cb < 2; ++cb) {
                int nl = 32 * wc + 16 * cb + li;
                float bv_ = bias[n0 + nl];
#pragma unroll
                for (int r = 0; r < 4; ++r) {
                    int ml = 32 * wr + 16 * ra + 4 * g + r;
                    Cs[nl * 72 + ml] = f2bf(acc[ra][cb][r] + bv_);
                }
            }
        __syncthreads();
        for (int c = tid; c < 512; c += 256) {
            int dl = c >> 3, s8 = (c & 7) * 8;
            short8v vv = *reinterpret_cast<const short8v*>(&Cs[dl * 72 + s8]);
            *reinterpret_cast<short8v*>(
                &vto[(((size_t)bidx * HH + h) * DD + dl) * SS + (m0 & 511) + s8]) = vv;
        }
    }
}

// ---------------- K1: scores+exp+bucket+rowsum -> Pbuf (aug 640 cols), rowsum ----------------
// vs round 7: (1) ds_add_f32 HW atomics (ldsAdd) instead of CAS-loop atomicAdd,
// (2) per-kt counted vmcnt that never drains the P-stores (6/22/16),
// (3) mask from LDS, arc via rolling 1-ahead register pipe (no 48-reg hoist).
__global__ __launch_bounds__(256, 2) void scores_kernel(
    const short* __restrict__ qb, const short* __restrict__ kb,
    const unsigned int* __restrict__ arcQ, const float* __restrict__ maskp,
    const short* __restrict__ lnkb,
    short* __restrict__ Pbuf, float* __restrict__ rowsum, int bh0) {
    __shared__ short Ks[2][64][64];      // 16 KB
    __shared__ float qlds[64][84];       // 21 KB
    __shared__ float bucket[64][96];     // 24 KB
    __shared__ float maskL[512];         // 2 KB
    __shared__ float rowsumL[64];

    const int tid = threadIdx.x;
    const int w = tid >> 6, lane = tid & 63;
    const int li = lane & 15, g = lane >> 4;
    const int wr = w >> 1, wc = w & 1;
    const int bx = blockIdx.x;
    const int bL = bx & 3, rest = bx >> 2;
    const int h = rest % HH, qt = rest / HH;
    const int b = bh0 / HH + bL;
    const int bh = b * HH + h;
    const int bhL = bh - bh0;
    const int q0 = qt * 64;

    const short* kbp = kb + (size_t)bh * SS * DD;
    short* pbp = Pbuf + (size_t)bhL * SS * 640;
    const int q4base = (q0 + 32 * wr) >> 2;
    const unsigned int* arcbase = arcQ + (size_t)b * 128 * SS;

    // Q fragments (A): rows 32wr+16ra+li
    short8v af[2][2];
#pragma unroll
    for (int ra = 0; ra < 2; ++ra) {
        const short* base = qb + ((size_t)bh * SS + q0 + 32 * wr + 16 * ra + li) * DD + 8 * g;
        af[ra][0] = *reinterpret_cast<const short8v*>(base);
        af[ra][1] = *reinterpret_cast<const short8v*>(base + 32);
    }
    // mask -> LDS
    for (int i = tid; i < SS; i += 256) maskL[i] = maskp[(size_t)b * SS + i];
    // arc rolling pipe: issue av(0)
    unsigned int avc[2][2], avn[2][2];
#pragma unroll
    for (int ra = 0; ra < 2; ++ra)
#pragma unroll
        for (int cb = 0; cb < 2; ++cb)
            avn[ra][cb] = arcbase[(size_t)(q4base + 4 * ra + g) * SS + 32 * wc + 16 * cb + li];
    // stage K(0)
#pragma unroll
    for (int j = 0; j < 2; ++j) {
        int c = tid + 256 * j, row = c >> 3, s8 = (c & 7) ^ (row & 7);
        gload16(kbp + (size_t)row * DD + s8 * 8, &Ks[0][0][0] + c * 8);
    }
    for (int i = tid; i < 64 * 96; i += 256) (&bucket[0][0])[i] = 0.f;
    if (tid < 64) rowsumL[tid] = 0.f;

    // qrel via MFMA (wc==0 waves compute their wr-half rows)
    if (wc == 0) {
#pragma unroll
        for (int ra = 0; ra < 2; ++ra)
#pragma unroll
            for (int ct = 0; ct < 6; ++ct) {
                f32x4 a = {0.f, 0.f, 0.f, 0.f};
                short8v b0 = *reinterpret_cast<const short8v*>(&lnkb[(16 * ct + li) * DD + 8 * g]);
                short8v b1 = *reinterpret_cast<const short8v*>(&lnkb[(16 * ct + li) * DD + 32 + 8 * g]);
                a = MFMA16(af[ra][0], b0, a);
                a = MFMA16(af[ra][1], b1, a);
                int col = 16 * ct + li;
                if (col < 84)
#pragma unroll
                    for (int r = 0; r < 4; ++r)
                        qlds[32 * wr + 16 * ra + 4 * g + r][col] = a[r];
            }
    }
    asm volatile("s_waitcnt lgkmcnt(0)" ::: "memory");
    __builtin_amdgcn_sched_barrier(0);

    float rsum[2][4];
#pragma unroll
    for (int ra = 0; ra < 2; ++ra)
#pragma unroll
        for (int r = 0; r < 4; ++r) rsum[ra][r] = 0.f;

#pragma unroll
    for (int kt = 0; kt < 8; ++kt) {
        const int cur = kt & 1, nxt = cur ^ 1;
        const int kb0 = kt * 64;

        // rotate arc pipe
#pragma unroll
        for (int ra = 0; ra < 2; ++ra)
#pragma unroll
            for (int cb = 0; cb < 2; ++cb) avc[ra][cb] = avn[ra][cb];

        if (kt < 7) {
            // issue av(kt+1) then K(kt+1)
#pragma unroll
            for (int ra = 0; ra < 2; ++ra)
#pragma unroll
                for (int cb = 0; cb < 2; ++cb)
                    avn[ra][cb] = arcbase[(size_t)(q4base + 4 * ra + g) * SS +
                                          (kt + 1) * 64 + 32 * wc + 16 * cb + li];
#pragma unroll
            for (int j = 0; j < 2; ++j) {
                int c = tid + 256 * j, row = c >> 3, s8 = (c & 7) ^ (row & 7);
                gload16(kbp + (size_t)(kb0 + 64 + row) * DD + s8 * 8, &Ks[nxt][0][0] + c * 8);
            }
            __builtin_amdgcn_sched_barrier(0);
            // retire K(kt) only: leave stores(16) + av(kt+1)(4) + K(kt+1)(2) in flight
            if (kt == 0) asm volatile("s_waitcnt vmcnt(6)" ::: "memory");
            else         asm volatile("s_waitcnt vmcnt(22)" ::: "memory");
        } else {
            asm volatile("s_waitcnt vmcnt(16)" ::: "memory");  // K(7)2 of [K(7)2+stores16]
        }
        __builtin_amdgcn_sched_barrier(0);
        __builtin_amdgcn_s_barrier();
        __builtin_amdgcn_sched_barrier(0);

        // QK^T (K pre-scaled 0.125)
        f32x4 acc[2][2];
#pragma unroll
        for (int ra = 0; ra < 2; ++ra)
#pragma unroll
            for (int cb = 0; cb < 2; ++cb)
                for (int r = 0; r < 4; ++r) acc[ra][cb][r] = 0.f;
#pragma unroll
        for (int c = 0; c < 2; ++c) {
            short8v bf[2];
#pragma unroll
            for (int cb = 0; cb < 2; ++cb) {
                int rowb = 32 * wc + 16 * cb + li;
                int chunk = (4 * c + g) ^ (rowb & 7);
                bf[cb] = *reinterpret_cast<const short8v*>(&Ks[cur][rowb][chunk * 8]);
            }
#pragma unroll
            for (int ra = 0; ra < 2; ++ra)
#pragma unroll
                for (int cb = 0; cb < 2; ++cb)
                    acc[ra][cb] = MFMA16(af[ra][c], bf[cb], acc[ra][cb]);
        }

        // epilogue: exp + HW LDS atomic bucket + rowsum + P store (fire-and-forget)
#pragma unroll
        for (int ra = 0; ra < 2; ++ra)
#pragma unroll
            for (int cb = 0; cb < 2; ++cb) {
                const unsigned int a4 = avc[ra][cb];
                const int colk = kb0 + 32 * wc + 16 * cb + li;
                const float m = maskL[colk];
                const int rowb = 32 * wr + 16 * ra + 4 * g;
#pragma unroll
                for (int r = 0; r < 4; ++r) {
                    const int a_ = (a4 >> (8 * r)) & 255;
                    float s = acc[ra][cb][r] + qlds[rowb + r][a_] + m;
                    float p = __expf(s);
                    rsum[ra][r] += p;
                    ldsAdd(&bucket[rowb + r][a_], p);
                    pbp[(size_t)(q0 + rowb + r) * 640 + colk] = f2bf(p);
                }
            }

        __builtin_amdgcn_s_barrier();   // Ks[cur] reads done before next stage overwrites
        __builtin_amdgcn_sched_barrier(0);
    }

    // reduce rowsum over the 16-lane (li) group, then cross-wave via LDS
#pragma unroll
    for (int m = 1; m < 16; m <<= 1)
#pragma unroll
        for (int ra = 0; ra < 2; ++ra)
#pragma unroll
            for (int r = 0; r < 4; ++r) rsum[ra][r] += __shfl_xor(rsum[ra][r], m);
    if (li == 0) {
#pragma unroll
        for (int ra = 0; ra < 2; ++ra)
#pragma unroll
            for (int r = 0; r < 4; ++r)
                ldsAdd(&rowsumL[32 * wr + 16 * ra + 4 * g + r], rsum[ra][r]);
    }
    __syncthreads();

    // bucket -> aug cols of Pbuf; rowsum -> global
    for (int i = tid; i < 64 * 96; i += 256) {
        int row = i / 96, l = i - row * 96;
        pbp[(size_t)(q0 + row) * 640 + 512 + l] = f2bf(bucket[row][l]);
    }
    if (tid < 64) rowsum[(size_t)bh * SS + q0 + tid] = rowsumL[tid];
}

// ---------------- K2: out = P_aug @ [V ; lnvT128] * (1/rowsum) ----------------
__global__ __launch_bounds__(256, 2) void pv_kernel(
    const short* __restrict__ Pbuf, const short* __restrict__ vt,
    const short* __restrict__ lnvT128, const float* __restrict__ rowsum,
    float* __restrict__ outp, int bh0) {
    __shared__ short As[2][64][64];
    __shared__ short Bs[2][64][64];

    const int tid = threadIdx.x;
    const int w = tid >> 6, lane = tid & 63;
    const int li = lane & 15, g = lane >> 4;
    const int wr = w >> 1, wc = w & 1;
    const int bx = blockIdx.x;
    const int bL = bx & 3, rest = bx >> 2;
    const int h = rest % HH, qt = rest / HH;
    const int b = bh0 / HH + bL;
    const int bh = b * HH + h;
    const int bhL = bh - bh0;
    const int q0 = qt * 64;

    const short* pbp = Pbuf + (size_t)bhL * SS * 640;
    const short* vbp = vt + (size_t)bh * DD * SS;

#pragma unroll
    for (int j = 0; j < 2; ++j) {
        int c = tid + 256 * j, row = c >> 3, s8 = (c & 7) ^ (row & 7);
        gload16(pbp + (size_t)(q0 + row) * 640 + s8 * 8, &As[0][0][0] + c * 8);
        gload16(vbp + (size_t)row * SS + s8 * 8, &Bs[0][0][0] + c * 8);
    }

    f32x4 acc[2][2];
#pragma unroll
    for (int ra = 0; ra < 2; ++ra)
#pragma unroll
        for (int cb = 0; cb < 2; ++cb)
            for (int r = 0; r < 4; ++r) acc[ra][cb][r] = 0.f;

#pragma unroll
    for (int it = 0; it < 10; ++it) {
        const int cur = it & 1, nxt = cur ^ 1;

        if (it < 9) {
            const int kk = (it + 1) * 64;
#pragma unroll
            for (int j = 0; j < 2; ++j) {
                int c = tid + 256 * j, row = c >> 3, s8 = (c & 7) ^ (row & 7);
                gload16(pbp + (size_t)(q0 + row) * 640 + kk + s8 * 8, &As[nxt][0][0] + c * 8);
                if (kk < 512)
                    gload16(vbp + (size_t)row * SS + kk + s8 * 8, &Bs[nxt][0][0] + c * 8);
                else
                    gload16(lnvT128 + (size_t)row * 128 + (kk - 512) + s8 * 8, &Bs[nxt][0][0] + c * 8);
            }
            __builtin_amdgcn_sched_barrier(0);
            asm volatile("s_waitcnt vmcnt(4)" ::: "memory");
        } else {
            asm volatile("s_waitcnt vmcnt(0)" ::: "memory");
        }
        __builtin_amdgcn_sched_barrier(0);
        __builtin_amdgcn_s_barrier();
        __builtin_amdgcn_sched_barrier(0);

#pragma unroll
        for (int c = 0; c < 2; ++c) {
            short8v af[2], bf[2];
#pragma unroll
            for (int ra = 0; ra < 2; ++ra) {
                int row = 32 * wr + 16 * ra + li;
                int chunk = (4 * c + g) ^ (row & 7);
                af[ra] = *reinterpret_cast<const short8v*>(&As[cur][row][chunk * 8]);
            }
#pragma unroll
            for (int cb = 0; cb < 2; ++cb) {
                int rowb = 32 * wc + 16 * cb + li;
                int chunk = (4 * c + g) ^ (rowb & 7);
                bf[cb] = *reinterpret_cast<const short8v*>(&Bs[cur][rowb][chunk * 8]);
            }
#pragma unroll
            for (int ra = 0; ra < 2; ++ra)
#pragma unroll
                for (int cb = 0; cb < 2; ++cb)
                    acc[ra][cb] = MFMA16(af[ra], bf[cb], acc[ra][cb]);
        }

        __builtin_amdgcn_s_barrier();
        __builtin_amdgcn_sched_barrier(0);
    }

    float invv[2][4];
#pragma unroll
    for (int ra = 0; ra < 2; ++ra)
#pragma unroll
        for (int r = 0; r < 4; ++r)
            invv[ra][r] = 1.f / rowsum[(size_t)bh * SS + q0 + 32 * wr + 16 * ra + 4 * g + r];

#pragma unroll
    for (int ra = 0; ra < 2; ++ra)
#pragma unroll
        for (int cb = 0; cb < 2; ++cb) {
            int col = 32 * wc + 16 * cb + li;
#pragma unroll
            for (int r = 0; r < 4; ++r) {
                int row = q0 + 32 * wr + 16 * ra + 4 * g + r;
                outp[((size_t)b * SS + row) * HIDV + h * DD + col] =
                    acc[ra][cb][r] * invv[ra][r];
            }
        }
}

// ---------------- launcher ----------------
extern "C" void kernel_launch(void* const* d_in, const int* in_sizes, int n_in,
                              void* d_out, int out_size, void* d_ws, size_t ws_size,
                              hipStream_t stream) {
    const float* hidden = (const float*)d_in[0];
    const float* mask   = (const float*)d_in[1];
    const int*   arc    = (const int*)d_in[2];
    const float* Wq = (const float*)d_in[3];
    const float* bq = (const float*)d_in[4];
    const float* Wk = (const float*)d_in[5];
    const float* bk = (const float*)d_in[6];
    const float* Wv = (const float*)d_in[7];
    const float* bv = (const float*)d_in[8];
    const float* rel_k = (const float*)d_in[9];
    const float* rel_v = (const float*)d_in[10];
    const float* lng_k = (const float*)d_in[11];
    const float* lnb_k = (const float*)d_in[12];
    const float* lng_v = (const float*)d_in[13];
    const float* lnb_v = (const float*)d_in[14];
    float* out = (float*)d_out;

    char* p = (char*)d_ws;
    auto carve = [&](size_t bytes) { char* r = p; p += (bytes + 255) & ~(size_t)255; return r; };
    short* lnkb    = (short*)carve((size_t)96 * DD * 2);
    short* lnvT128 = (short*)carve((size_t)DD * 128 * 2);
    const size_t per = (size_t)BB * HH * SS * DD;
    short* qbuf = (short*)carve(per * 2);
    short* kbuf = (short*)carve(per * 2);
    short* vtb  = (short*)carve(per * 2);
    unsigned int* arcQ = (unsigned int*)carve((size_t)BB * 128 * SS * 4);
    float* rowsum = (float*)carve((size_t)BB * HH * SS * 4);
    char* tail = p;   // everything below is dead by the time K1 runs
    short* hbf  = (short*)carve((size_t)BB * SS * HIDV * 2);
    short* WqT  = (short*)carve((size_t)HIDV * HIDV * 2);
    short* WkT  = (short*)carve((size_t)HIDV * HIDV * 2);
    short* WvT  = (short*)carve((size_t)HIDV * HIDV * 2);
    short* Pbuf = (short*)tail;   // 48 bh * 512 * 640 * 2B = 31.5 MB, aliases hbf/W region

    prep_ln_kernel<<<1, 256, 0, stream>>>(rel_k, rel_v, lng_k, lnb_k, lng_v, lnb_v, lnkb, lnvT128);
    conv_hidden_kernel<<<(BB * SS * HIDV) / 1024, 256, 0, stream>>>(hidden, hbf);
    transw_kernel<<<dim3(24, 24, 3), 256, 0, stream>>>(Wq, Wk, Wv, WqT, WkT, WvT);
    arcq_kernel<<<dim3(8, 8, BB), 256, 0, stream>>>(arc, arcQ);
    qkv_gemm_kernel<<<dim3(HIDV / 64, (BB * SS) / 64, 3), 256, 0, stream>>>(
        hbf, WqT, WkT, WvT, bq, bk, bv, qbuf, kbuf, vtb);
    for (int chunk = 0; chunk < 2; ++chunk) {
        int bh0 = chunk * 48;
        scores_kernel<<<dim3(384), 256, 0, stream>>>(qbuf, kbuf, arcQ, mask, lnkb,
                                                     Pbuf, rowsum, bh0);
        pv_kernel<<<dim3(384), 256, 0, stream>>>(Pbuf, vtb, lnvT128, rowsum, out, bh0);
    }
}

// Round 9
// 242.538 us; speedup vs baseline: 1.0963x; 1.0963x over previous
//
#include <hip/hip_runtime.h>
#include <hip/hip_bf16.h>

#define BB 8
#define SS 512
#define HIDV 768
#define HH 12
#define DD 64
#define LV 81

typedef __attribute__((ext_vector_type(8))) short short8v;
typedef __attribute__((ext_vector_type(4))) short short4v;
typedef __attribute__((ext_vector_type(4))) float f32x4;

#define MFMA16(a, b, c) __builtin_amdgcn_mfma_f32_16x16x32_bf16(a, b, c, 0, 0, 0)

__device__ __forceinline__ short f2bf(float f) {
    __hip_bfloat16 h = __float2bfloat16(f);
    return *reinterpret_cast<short*>(&h);
}
__device__ __forceinline__ void gload16(const void* g, void* l) {
    __builtin_amdgcn_global_load_lds((const __attribute__((address_space(1))) void*)g,
                                     (__attribute__((address_space(3))) void*)l, 16, 0, 0);
}

// ---------------- LN tables -> lnkb bf16 [96][64], lnvT128 bf16 [64][128] ----------------
__global__ __launch_bounds__(256) void prep_ln_kernel(
    const float* __restrict__ rel_k, const float* __restrict__ rel_v,
    const float* __restrict__ gk, const float* __restrict__ bk,
    const float* __restrict__ gv, const float* __restrict__ bv,
    short* __restrict__ lnkb, short* __restrict__ lnvT128) {
    __shared__ float ln_lds[2 * LV][DD];
    int t = threadIdx.x;
    if (t < 2 * LV) {
        bool isv = (t >= LV);
        int r = isv ? t - LV : t;
        const float* row = (isv ? rel_v : rel_k) + r * DD;
        const float* g = isv ? gv : gk;
        const float* be = isv ? bv : bk;
        float mu = 0.f;
        for (int d = 0; d < DD; ++d) mu += row[d];
        mu *= (1.f / DD);
        float var = 0.f;
        for (int d = 0; d < DD; ++d) { float x = row[d] - mu; var += x * x; }
        var *= (1.f / DD);
        float rs = rsqrtf(var + 1e-5f);
        for (int d = 0; d < DD; ++d) ln_lds[t][d] = (row[d] - mu) * rs * g[d] + be[d];
    }
    __syncthreads();
    for (int i = t; i < 96 * DD; i += 256) {
        int l = i >> 6, d = i & 63;
        lnkb[i] = (l < LV) ? f2bf(ln_lds[l][d]) : (short)0;
    }
    for (int i = t; i < DD * 128; i += 256) {
        int d = i >> 7, l = i & 127;
        lnvT128[i] = (l < LV) ? f2bf(ln_lds[LV + l][d]) : (short)0;
    }
}

// ---------------- hidden f32 -> bf16 ----------------
__global__ __launch_bounds__(256) void conv_hidden_kernel(const float* __restrict__ in,
                                                          short* __restrict__ out) {
    int i = (blockIdx.x * 256 + threadIdx.x) * 4;
    float4 v = *reinterpret_cast<const float4*>(&in[i]);
    short4v o; o[0] = f2bf(v.x); o[1] = f2bf(v.y); o[2] = f2bf(v.z); o[3] = f2bf(v.w);
    *reinterpret_cast<short4v*>(&out[i]) = o;
}

// ---------------- W [k][n] f32 -> WT [n][k] bf16 (x3 via z) ----------------
__global__ __launch_bounds__(256) void transw_kernel(
    const float* __restrict__ Wq, const float* __restrict__ Wk, const float* __restrict__ Wv,
    short* __restrict__ WqT, short* __restrict__ WkT, short* __restrict__ WvT) {
    const float* W; short* O;
    if (blockIdx.z == 0) { W = Wq; O = WqT; }
    else if (blockIdx.z == 1) { W = Wk; O = WkT; }
    else { W = Wv; O = WvT; }
    __shared__ float tile[32][33];
    int k0 = blockIdx.y * 32, n0 = blockIdx.x * 32;
    int t = threadIdx.x;
    int r = t >> 3, c4 = (t & 7) * 4;
    float4 v = *reinterpret_cast<const float4*>(&W[(size_t)(k0 + r) * HIDV + n0 + c4]);
    tile[r][c4 + 0] = v.x; tile[r][c4 + 1] = v.y; tile[r][c4 + 2] = v.z; tile[r][c4 + 3] = v.w;
    __syncthreads();
    short4v o;
    o[0] = f2bf(tile[c4 + 0][r]); o[1] = f2bf(tile[c4 + 1][r]);
    o[2] = f2bf(tile[c4 + 2][r]); o[3] = f2bf(tile[c4 + 3][r]);
    *reinterpret_cast<short4v*>(&O[(size_t)(n0 + r) * HIDV + k0 + c4]) = o;
}

// ---------------- QKV GEMM bf16 MFMA (unchanged, proven) ----------------
__global__ __launch_bounds__(256) void qkv_gemm_kernel(
    const short* __restrict__ Abf,
    const short* __restrict__ WqT, const short* __restrict__ WkT, const short* __restrict__ WvT,
    const float* __restrict__ bq, const float* __restrict__ bk, const float* __restrict__ bv,
    short* __restrict__ qo, short* __restrict__ ko, short* __restrict__ vto) {
    const short* Bt; const float* bias;
    int z = blockIdx.z;
    if (z == 0) { Bt = WqT; bias = bq; }
    else if (z == 1) { Bt = WkT; bias = bk; }
    else { Bt = WvT; bias = bv; }

    __shared__ short smem[8192];
    short* As = smem;
    short* Bs = smem + 4096;

    const int tid = threadIdx.x;
    const int lane = tid & 63, w = tid >> 6;
    const int li = lane & 15, g = lane >> 4;
    const int wr = w >> 1, wc = w & 1;
    const int m0 = blockIdx.y * 64, n0 = blockIdx.x * 64;

    f32x4 acc[2][2];
    for (int ra = 0; ra < 2; ++ra)
        for (int cb = 0; cb < 2; ++cb)
            for (int r = 0; r < 4; ++r) acc[ra][cb][r] = 0.f;

#pragma unroll 1
    for (int k0 = 0; k0 < HIDV; k0 += 64) {
#pragma unroll
        for (int j = 0; j < 2; ++j) {
            int c = j * 256 + tid;
            int row = c >> 3, s = c & 7;
            int src = s ^ (row & 7);
            gload16(Abf + (size_t)(m0 + row) * HIDV + k0 + src * 8, As + c * 8);
            gload16(Bt + (size_t)(n0 + row) * HIDV + k0 + src * 8, Bs + c * 8);
        }
        __syncthreads();
#pragma unroll
        for (int c = 0; c < 2; ++c) {
            short8v af[2], bf[2];
#pragma unroll
            for (int ra = 0; ra < 2; ++ra) {
                int row = 32 * wr + 16 * ra + li;
                int chunk = (4 * c + g) ^ (row & 7);
                af[ra] = *reinterpret_cast<const short8v*>(&As[row * 64 + chunk * 8]);
            }
#pragma unroll
            for (int cb = 0; cb < 2; ++cb) {
                int rowb = 32 * wc + 16 * cb + li;
                int chunk = (4 * c + g) ^ (rowb & 7);
                bf[cb] = *reinterpret_cast<const short8v*>(&Bs[rowb * 64 + chunk * 8]);
            }
#pragma unroll
            for (int ra = 0; ra < 2; ++ra)
#pragma unroll
                for (int cb = 0; cb < 2; ++cb)
                    acc[ra][cb] = MFMA16(af[ra], bf[cb], acc[ra][cb]);
        }
        __syncthreads();
    }

    const int h = n0 >> 6;
    const int bidx = m0 >> 9;
    if (z < 2) {
        short* dst = (z == 0) ? qo : ko;
        float sc = (z == 0) ? 1.f : 0.125f;
#pragma unroll
        for (int ra = 0; ra < 2; ++ra)
#pragma unroll
            for (int cb = 0; cb < 2; ++cb) {
                int n = 32 * wc + 16 * cb + li;
                float bv_ = bias[n0 + n];
#pragma unroll
                for (int r = 0; r < 4; ++r) {
                    int m = m0 + 32 * wr + 16 * ra + 4 * g + r;
                    int s = m & 511;
                    dst[(((size_t)bidx * HH + h) * SS + s) * DD + n] =
                        f2bf((acc[ra][cb][r] + bv_) * sc);
                }
            }
    } else {
        short* Cs = smem;
#pragma unroll
        for (int ra = 0; ra < 2; ++ra)
#pragma unroll
            for (int cb = 0; cb < 2; ++cb) {
                int nl = 32 * wc + 16 * cb + li;
                float bv_ = bias[n0 + nl];
#pragma unroll
                for (int r = 0; r < 4; ++r) {
                    int ml = 32 * wr + 16 * ra + 4 * g + r;
                    Cs[nl * 72 + ml] = f2bf(acc[ra][cb][r] + bv_);
                }
            }
        __syncthreads();
        for (int c = tid; c < 512; c += 256) {
            int dl = c >> 3, s8 = (c & 7) * 8;
            short8v vv = *reinterpret_cast<const short8v*>(&Cs[dl * 72 + s8]);
            *reinterpret_cast<short8v*>(
                &vto[(((size_t)bidx * HH + h) * DD + dl) * SS + (m0 & 511) + s8]) = vv;
        }
    }
}

// ---------------- qrelG[bh][512][96] f32 = Q @ lnkb^T via MFMA ----------------
__global__ __launch_bounds__(256) void qrelg_kernel(const short* __restrict__ qb,
                                                    const short* __restrict__ lnkb,
                                                    float* __restrict__ qrelG) {
    const int tid = threadIdx.x;
    const int w = tid >> 6, lane = tid & 63;
    const int li = lane & 15, g = lane >> 4;
    const int bx = blockIdx.x;
    const int bh = bx >> 3, qt = bx & 7;
    const int q0 = qt * 64 + 16 * w;

    const short* base = qb + ((size_t)bh * SS + q0 + li) * DD + 8 * g;
    short8v a0 = *reinterpret_cast<const short8v*>(base);
    short8v a1 = *reinterpret_cast<const short8v*>(base + 32);
#pragma unroll
    for (int ct = 0; ct < 6; ++ct) {
        f32x4 a = {0.f, 0.f, 0.f, 0.f};
        short8v b0 = *reinterpret_cast<const short8v*>(&lnkb[(16 * ct + li) * DD + 8 * g]);
        short8v b1 = *reinterpret_cast<const short8v*>(&lnkb[(16 * ct + li) * DD + 32 + 8 * g]);
        a = MFMA16(a0, b0, a);
        a = MFMA16(a1, b1, a);
#pragma unroll
        for (int r = 0; r < 4; ++r)
            qrelG[((size_t)bh * SS + q0 + 4 * g + r) * 96 + 16 * ct + li] = a[r];
    }
}

// ---------------- qk: S[bhL][512][512] f32 = Q @ K^T (K pre-scaled 1/8) ----------------
__global__ __launch_bounds__(256, 2) void qk_kernel(
    const short* __restrict__ qb, const short* __restrict__ kb,
    float* __restrict__ Sbuf, int bh0) {
    __shared__ short Ks[2][64][64];

    const int tid = threadIdx.x;
    const int w = tid >> 6, lane = tid & 63;
    const int li = lane & 15, g = lane >> 4;
    const int wr = w >> 1, wc = w & 1;
    const int bx = blockIdx.x;
    const int bhL = bx >> 3, qt = bx & 7;
    const int bh = bh0 + bhL;
    const int q0 = qt * 64;

    const short* kbp = kb + (size_t)bh * SS * DD;
    float* sbp = Sbuf + (size_t)bhL * SS * SS;

#pragma unroll
    for (int j = 0; j < 2; ++j) {
        int c = tid + 256 * j, row = c >> 3, s8 = (c & 7) ^ (row & 7);
        gload16(kbp + (size_t)row * DD + s8 * 8, &Ks[0][0][0] + c * 8);
    }

    short8v af[2][2];
#pragma unroll
    for (int ra = 0; ra < 2; ++ra) {
        const short* base = qb + ((size_t)bh * SS + q0 + 32 * wr + 16 * ra + li) * DD + 8 * g;
        af[ra][0] = *reinterpret_cast<const short8v*>(base);
        af[ra][1] = *reinterpret_cast<const short8v*>(base + 32);
    }

#pragma unroll
    for (int kt = 0; kt < 8; ++kt) {
        const int cur = kt & 1, nxt = cur ^ 1;
        const int kb0 = kt * 64;

        if (kt < 7) {
#pragma unroll
            for (int j = 0; j < 2; ++j) {
                int c = tid + 256 * j, row = c >> 3, s8 = (c & 7) ^ (row & 7);
                gload16(kbp + (size_t)(kb0 + 64 + row) * DD + s8 * 8, &Ks[nxt][0][0] + c * 8);
            }
            __builtin_amdgcn_sched_barrier(0);
            if (kt == 0) asm volatile("s_waitcnt vmcnt(2)" ::: "memory");
            else         asm volatile("s_waitcnt vmcnt(18)" ::: "memory");
        } else {
            asm volatile("s_waitcnt vmcnt(16)" ::: "memory");
        }
        __builtin_amdgcn_sched_barrier(0);
        __builtin_amdgcn_s_barrier();
        __builtin_amdgcn_sched_barrier(0);

        f32x4 acc[2][2];
#pragma unroll
        for (int ra = 0; ra < 2; ++ra)
#pragma unroll
            for (int cb = 0; cb < 2; ++cb)
                for (int r = 0; r < 4; ++r) acc[ra][cb][r] = 0.f;
#pragma unroll
        for (int c = 0; c < 2; ++c) {
            short8v bf[2];
#pragma unroll
            for (int cb = 0; cb < 2; ++cb) {
                int rowb = 32 * wc + 16 * cb + li;
                int chunk = (4 * c + g) ^ (rowb & 7);
                bf[cb] = *reinterpret_cast<const short8v*>(&Ks[cur][rowb][chunk * 8]);
            }
#pragma unroll
            for (int ra = 0; ra < 2; ++ra)
#pragma unroll
                for (int cb = 0; cb < 2; ++cb)
                    acc[ra][cb] = MFMA16(af[ra][c], bf[cb], acc[ra][cb]);
        }

        // plain coalesced f32 stores of raw S
#pragma unroll
        for (int ra = 0; ra < 2; ++ra)
#pragma unroll
            for (int cb = 0; cb < 2; ++cb) {
                const int colk = kb0 + 32 * wc + 16 * cb + li;
                const int rowb = q0 + 32 * wr + 16 * ra + 4 * g;
#pragma unroll
                for (int r = 0; r < 4; ++r)
                    sbp[(size_t)(rowb + r) * SS + colk] = acc[ra][cb][r];
            }

        __builtin_amdgcn_s_barrier();
        __builtin_amdgcn_sched_barrier(0);
    }
}

// ---------------- exp: P=exp(S+qrel+mask), buckets, rowsum. High-TLP elementwise ----------------
__global__ __launch_bounds__(256) void exp_kernel(
    const float* __restrict__ Sbuf, const int* __restrict__ arc,
    const float* __restrict__ qrelG, const float* __restrict__ maskp,
    short* __restrict__ Pbuf, float* __restrict__ rowsum, int bh0) {
    __shared__ float bucket[16][100];

    const int tid = threadIdx.x;
    const int bx = blockIdx.x;
    const int bhL = bx >> 5, rb = bx & 31;
    const int bh = bh0 + bhL;
    const int b = bh / HH;

    for (int i = tid; i < 16 * 100; i += 256) (&bucket[0][0])[i] = 0.f;
    __syncthreads();

    const int col2 = tid * 2;
#pragma unroll 4
    for (int e = 0; e < 16; ++e) {
        const int grow = rb * 16 + e;
        float2 s2 = *reinterpret_cast<const float2*>(
            &Sbuf[((size_t)bhL * SS + grow) * SS + col2]);
        int2 a2 = *reinterpret_cast<const int2*>(
            &arc[((size_t)b * SS + grow) * SS + col2]);
        float2 m2 = *reinterpret_cast<const float2*>(&maskp[(size_t)b * SS + col2]);
        const float* qr = &qrelG[((size_t)bh * SS + grow) * 96];
        float p0 = __expf(s2.x + qr[a2.x] + m2.x);
        float p1 = __expf(s2.y + qr[a2.y] + m2.y);
        unsafeAtomicAdd(&bucket[e][a2.x], p0);
        unsafeAtomicAdd(&bucket[e][a2.y], p1);
        unsigned int packed = (unsigned int)(unsigned short)f2bf(p0) |
                              ((unsigned int)(unsigned short)f2bf(p1) << 16);
        *reinterpret_cast<unsigned int*>(
            &Pbuf[((size_t)bhL * SS + grow) * 640 + col2]) = packed;
    }
    __syncthreads();

    // buckets -> aug cols [512..639] (zeros past 96); rowsum = sum of buckets
    for (int i = tid; i < 16 * 128; i += 256) {
        int row = i >> 7, l = i & 127;
        float v = (l < 96) ? bucket[row][l] : 0.f;
        Pbuf[((size_t)bhL * SS + rb * 16 + row) * 640 + 512 + l] = f2bf(v);
    }
    if (tid < 16) {
        float s = 0.f;
        for (int l = 0; l < LV; ++l) s += bucket[tid][l];
        rowsum[(size_t)bh * SS + rb * 16 + tid] = s;
    }
}

// ---------------- pv: out = P_aug @ [V ; lnvT128] * (1/rowsum) ----------------
__global__ __launch_bounds__(256, 2) void pv_kernel(
    const short* __restrict__ Pbuf, const short* __restrict__ vt,
    const short* __restrict__ lnvT128, const float* __restrict__ rowsum,
    float* __restrict__ outp, int bh0) {
    __shared__ short As[2][64][64];
    __shared__ short Bs[2][64][64];

    const int tid = threadIdx.x;
    const int w = tid >> 6, lane = tid & 63;
    const int li = lane & 15, g = lane >> 4;
    const int wr = w >> 1, wc = w & 1;
    const int bx = blockIdx.x;
    const int bhL = bx >> 3, qt = bx & 7;
    const int bh = bh0 + bhL;
    const int b = bh / HH, h = bh % HH;
    const int q0 = qt * 64;

    const short* pbp = Pbuf + (size_t)bhL * SS * 640;
    const short* vbp = vt + (size_t)bh * DD * SS;

#pragma unroll
    for (int j = 0; j < 2; ++j) {
        int c = tid + 256 * j, row = c >> 3, s8 = (c & 7) ^ (row & 7);
        gload16(pbp + (size_t)(q0 + row) * 640 + s8 * 8, &As[0][0][0] + c * 8);
        gload16(vbp + (size_t)row * SS + s8 * 8, &Bs[0][0][0] + c * 8);
    }

    f32x4 acc[2][2];
#pragma unroll
    for (int ra = 0; ra < 2; ++ra)
#pragma unroll
        for (int cb = 0; cb < 2; ++cb)
            for (int r = 0; r < 4; ++r) acc[ra][cb][r] = 0.f;

#pragma unroll
    for (int it = 0; it < 10; ++it) {
        const int cur = it & 1, nxt = cur ^ 1;

        if (it < 9) {
            const int kk = (it + 1) * 64;
#pragma unroll
            for (int j = 0; j < 2; ++j) {
                int c = tid + 256 * j, row = c >> 3, s8 = (c & 7) ^ (row & 7);
                gload16(pbp + (size_t)(q0 + row) * 640 + kk + s8 * 8, &As[nxt][0][0] + c * 8);
                if (kk < 512)
                    gload16(vbp + (size_t)row * SS + kk + s8 * 8, &Bs[nxt][0][0] + c * 8);
                else
                    gload16(lnvT128 + (size_t)row * 128 + (kk - 512) + s8 * 8, &Bs[nxt][0][0] + c * 8);
            }
            __builtin_amdgcn_sched_barrier(0);
            asm volatile("s_waitcnt vmcnt(4)" ::: "memory");
        } else {
            asm volatile("s_waitcnt vmcnt(0)" ::: "memory");
        }
        __builtin_amdgcn_sched_barrier(0);
        __builtin_amdgcn_s_barrier();
        __builtin_amdgcn_sched_barrier(0);

#pragma unroll
        for (int c = 0; c < 2; ++c) {
            short8v af[2], bf[2];
#pragma unroll
            for (int ra = 0; ra < 2; ++ra) {
                int row = 32 * wr + 16 * ra + li;
                int chunk = (4 * c + g) ^ (row & 7);
                af[ra] = *reinterpret_cast<const short8v*>(&As[cur][row][chunk * 8]);
            }
#pragma unroll
            for (int cb = 0; cb < 2; ++cb) {
                int rowb = 32 * wc + 16 * cb + li;
                int chunk = (4 * c + g) ^ (rowb & 7);
                bf[cb] = *reinterpret_cast<const short8v*>(&Bs[cur][rowb][chunk * 8]);
            }
#pragma unroll
            for (int ra = 0; ra < 2; ++ra)
#pragma unroll
                for (int cb = 0; cb < 2; ++cb)
                    acc[ra][cb] = MFMA16(af[ra], bf[cb], acc[ra][cb]);
        }

        __builtin_amdgcn_s_barrier();
        __builtin_amdgcn_sched_barrier(0);
    }

    float invv[2][4];
#pragma unroll
    for (int ra = 0; ra < 2; ++ra)
#pragma unroll
        for (int r = 0; r < 4; ++r)
            invv[ra][r] = 1.f / rowsum[(size_t)bh * SS + q0 + 32 * wr + 16 * ra + 4 * g + r];

#pragma unroll
    for (int ra = 0; ra < 2; ++ra)
#pragma unroll
        for (int cb = 0; cb < 2; ++cb) {
            int col = 32 * wc + 16 * cb + li;
#pragma unroll
            for (int r = 0; r < 4; ++r) {
                int row = q0 + 32 * wr + 16 * ra + 4 * g + r;
                outp[((size_t)b * SS + row) * HIDV + h * DD + col] =
                    acc[ra][cb][r] * invv[ra][r];
            }
        }
}

// ---------------- launcher ----------------
extern "C" void kernel_launch(void* const* d_in, const int* in_sizes, int n_in,
                              void* d_out, int out_size, void* d_ws, size_t ws_size,
                              hipStream_t stream) {
    const float* hidden = (const float*)d_in[0];
    const float* mask   = (const float*)d_in[1];
    const int*   arc    = (const int*)d_in[2];
    const float* Wq = (const float*)d_in[3];
    const float* bq = (const float*)d_in[4];
    const float* Wk = (const float*)d_in[5];
    const float* bk = (const float*)d_in[6];
    const float* Wv = (const float*)d_in[7];
    const float* bv = (const float*)d_in[8];
    const float* rel_k = (const float*)d_in[9];
    const float* rel_v = (const float*)d_in[10];
    const float* lng_k = (const float*)d_in[11];
    const float* lnb_k = (const float*)d_in[12];
    const float* lng_v = (const float*)d_in[13];
    const float* lnb_v = (const float*)d_in[14];
    float* out = (float*)d_out;

    char* p = (char*)d_ws;
    auto carve = [&](size_t bytes) { char* r = p; p += (bytes + 255) & ~(size_t)255; return r; };
    short* lnkb    = (short*)carve((size_t)96 * DD * 2);
    short* lnvT128 = (short*)carve((size_t)DD * 128 * 2);
    const size_t per = (size_t)BB * HH * SS * DD;
    short* qbuf = (short*)carve(per * 2);
    short* kbuf = (short*)carve(per * 2);
    short* vtb  = (short*)carve(per * 2);
    float* rowsum = (float*)carve((size_t)BB * HH * SS * 4);
    char* tail = p;  // aliased region

    // phase-1 residents of tail (dead after qkv_gemm):
    short* hbf  = (short*)tail;
    short* WqT  = hbf + (size_t)BB * SS * HIDV;
    short* WkT  = WqT + (size_t)HIDV * HIDV;
    short* WvT  = WkT + (size_t)HIDV * HIDV;
    // phase-2 residents of tail (written after qkv done):
    float* qrelG = (float*)tail;                                   // 96*512*96*4 = 18.9 MB
    char* tail2 = tail + (((size_t)96 * SS * 96 * 4 + 255) & ~(size_t)255);

    // adaptive chunk size by ws capacity
    size_t head_used = (size_t)(tail2 - (char*)d_ws);
    int C = 3;
    for (int cand = 48; cand >= 3; cand >>= 1) {
        size_t need = head_used + (size_t)cand * SS * SS * 4 + (size_t)cand * SS * 640 * 2;
        if (need <= ws_size && 96 % cand == 0) { C = cand; break; }
    }
    float* Sbuf = (float*)tail2;
    short* Pbuf = (short*)(tail2 + (((size_t)C * SS * SS * 4 + 255) & ~(size_t)255));

    prep_ln_kernel<<<1, 256, 0, stream>>>(rel_k, rel_v, lng_k, lnb_k, lng_v, lnb_v, lnkb, lnvT128);
    conv_hidden_kernel<<<(BB * SS * HIDV) / 1024, 256, 0, stream>>>(hidden, hbf);
    transw_kernel<<<dim3(24, 24, 3), 256, 0, stream>>>(Wq, Wk, Wv, WqT, WkT, WvT);
    qkv_gemm_kernel<<<dim3(HIDV / 64, (BB * SS) / 64, 3), 256, 0, stream>>>(
        hbf, WqT, WkT, WvT, bq, bk, bv, qbuf, kbuf, vtb);
    qrelg_kernel<<<dim3(96 * 8), 256, 0, stream>>>(qbuf, lnkb, qrelG);

    for (int bh0 = 0; bh0 < 96; bh0 += C) {
        qk_kernel<<<dim3(C * 8), 256, 0, stream>>>(qbuf, kbuf, Sbuf, bh0);
        exp_kernel<<<dim3(C * 32), 256, 0, stream>>>(Sbuf, arc, qrelG, mask, Pbuf, rowsum, bh0);
        pv_kernel<<<dim3(C * 8), 256, 0, stream>>>(Pbuf, vtb, lnvT128, rowsum, out, bh0);
    }
}